// Round 2
// baseline (619.431 us; speedup 1.0000x reference)
//
#include <hip/hip_runtime.h>
#include <hip/hip_bf16.h>
#include <cstdint>
#include <cstddef>

#define NQ 131072   // queries
#define MS 512      // memory slots
#define DD 256      // feature dim

// score GEMM tiling
#define BQ 128      // query rows per block
#define BM 128      // slot cols per chunk
#define DC 32       // depth chunk
#define PAD 132     // padded stride (floats) for transposed LDS tiles; 132*4=528 is 16B-aligned per row

// ---- monotone float <-> uint encoding for atomicMax on f32 ----
__device__ __forceinline__ unsigned enc_f32(float x) {
  unsigned u = __float_as_uint(x);
  return (u & 0x80000000u) ? ~u : (u | 0x80000000u);
}
__device__ __forceinline__ float dec_f32(unsigned u) {
  unsigned b = (u & 0x80000000u) ? (u & 0x7FFFFFFFu) : ~u;
  return __uint_as_float(b);
}

// ---- Kernel A: fp32 score GEMM (query @ keys^T) fused with row-argmax + col-max ----
__global__ __launch_bounds__(256) void score_kernel(
    const float* __restrict__ query, const float* __restrict__ keys,
    int* __restrict__ assign_out, float* __restrict__ sval_out,
    unsigned* __restrict__ colmax_enc)
{
  __shared__ float Qs[DC][PAD];   // transposed: Qs[d][row]
  __shared__ float Ks[DC][PAD];   // transposed: Ks[d][col]
  __shared__ float redV[BQ * 16];
  __shared__ int   redI[BQ * 16];

  const int tid = threadIdx.x;
  const int ty = tid >> 4;   // 0..15  -> rows ty*8..ty*8+7
  const int tx = tid & 15;   // 0..15  -> cols tx*8..tx*8+7
  const int q0 = blockIdx.x * BQ;

  float bestV = -3.4e38f;    // running row max (valid for tid < BQ, row = tid)
  int   bestI = 0;

  for (int mc = 0; mc < MS / BM; ++mc) {
    float acc[8][8];
#pragma unroll
    for (int i = 0; i < 8; ++i)
#pragma unroll
      for (int j = 0; j < 8; ++j) acc[i][j] = 0.f;

    for (int dc = 0; dc < DD; dc += DC) {
      __syncthreads();  // protect LDS tiles from previous iteration's readers
#pragma unroll
      for (int it = 0; it < 4; ++it) {
        const int r = (tid >> 3) + it * 32;   // 0..127
        const int d = (tid & 7) * 4;          // 0..28
        const float4 qv = *reinterpret_cast<const float4*>(
            &query[(size_t)(q0 + r) * DD + dc + d]);
        Qs[d + 0][r] = qv.x; Qs[d + 1][r] = qv.y;
        Qs[d + 2][r] = qv.z; Qs[d + 3][r] = qv.w;
        const float4 kv = *reinterpret_cast<const float4*>(
            &keys[(size_t)(mc * BM + r) * DD + dc + d]);
        Ks[d + 0][r] = kv.x; Ks[d + 1][r] = kv.y;
        Ks[d + 2][r] = kv.z; Ks[d + 3][r] = kv.w;
      }
      __syncthreads();
#pragma unroll
      for (int d = 0; d < DC; ++d) {
        float a[8], b[8];
        *reinterpret_cast<float4*>(&a[0]) = *reinterpret_cast<const float4*>(&Qs[d][ty * 8]);
        *reinterpret_cast<float4*>(&a[4]) = *reinterpret_cast<const float4*>(&Qs[d][ty * 8 + 4]);
        *reinterpret_cast<float4*>(&b[0]) = *reinterpret_cast<const float4*>(&Ks[d][tx * 8]);
        *reinterpret_cast<float4*>(&b[4]) = *reinterpret_cast<const float4*>(&Ks[d][tx * 8 + 4]);
#pragma unroll
        for (int i = 0; i < 8; ++i)
#pragma unroll
          for (int j = 0; j < 8; ++j)
            acc[i][j] = fmaf(a[i], b[j], acc[i][j]);
      }
    }

    // ---- per-row argmax over this 128-col chunk (first-index-on-tie semantics) ----
    __syncthreads();  // red buffers reused across mc
#pragma unroll
    for (int i = 0; i < 8; ++i) {
      float v = acc[i][0]; int jj = 0;
#pragma unroll
      for (int j = 1; j < 8; ++j)
        if (acc[i][j] > v) { v = acc[i][j]; jj = j; }   // strict >: keep earliest col
      redV[(ty * 8 + i) * 16 + tx] = v;
      redI[(ty * 8 + i) * 16 + tx] = mc * BM + tx * 8 + jj;
    }
    __syncthreads();
    if (tid < BQ) {
#pragma unroll
      for (int t = 0; t < 16; ++t) {                    // ascending tx: earliest wins
        float v = redV[tid * 16 + t];
        if (v > bestV) { bestV = v; bestI = redI[tid * 16 + t]; }
      }
    }
    __syncthreads();
    // ---- per-col max over this block's 128 rows ----
#pragma unroll
    for (int j = 0; j < 8; ++j) {
      float v = acc[0][j];
#pragma unroll
      for (int i = 1; i < 8; ++i) v = fmaxf(v, acc[i][j]);
      redV[(tx * 8 + j) * 16 + ty] = v;
    }
    __syncthreads();
    if (tid < BM) {
      float v = redV[tid * 16];
#pragma unroll
      for (int t = 1; t < 16; ++t) v = fmaxf(v, redV[tid * 16 + t]);
      atomicMax(&colmax_enc[mc * BM + tid], enc_f32(v));
    }
  }

  if (tid < BQ) {
    assign_out[q0 + tid] = bestI;
    sval_out[q0 + tid]   = bestV;
  }
}

// ---- Kernel B: weights + per-slot counts/positions ----
__global__ void weight_kernel(const float* __restrict__ sval,
                              const int* __restrict__ assign,
                              const unsigned* __restrict__ colmax_enc,
                              float* __restrict__ w,
                              int* __restrict__ pos,
                              int* __restrict__ count)
{
  int i = blockIdx.x * blockDim.x + threadIdx.x;
  if (i >= NQ) return;
  int a = assign[i];
  float cm = dec_f32(colmax_enc[a]);
  w[i] = expf(sval[i] - cm);              // == score_query[i,a] / col_max[a]
  pos[i] = atomicAdd(&count[a], 1);
}

// ---- Kernel B2: exclusive scan of 512 counts (single block) ----
__global__ void scan_kernel(const int* __restrict__ count, int* __restrict__ offset)
{
  __shared__ int s[MS];
  int t = threadIdx.x;
  int c = count[t];
  s[t] = c;
  __syncthreads();
  for (int off = 1; off < MS; off <<= 1) {
    int v = (t >= off) ? s[t - off] : 0;
    __syncthreads();
    s[t] += v;
    __syncthreads();
  }
  offset[t] = s[t] - c;
}

// ---- Kernel B3: CSR fill ----
__global__ void fill_kernel(const int* __restrict__ assign,
                            const int* __restrict__ pos,
                            const int* __restrict__ offset,
                            int* __restrict__ list)
{
  int i = blockIdx.x * blockDim.x + threadIdx.x;
  if (i >= NQ) return;
  int a = assign[i];
  list[offset[a] + pos[i]] = i;
}

// ---- Kernel C: per-slot gather-sum + add keys + L2 normalize + f32 store ----
__global__ __launch_bounds__(256) void update_kernel(
    const float* __restrict__ value, const float* __restrict__ keys,
    const float* __restrict__ w, const int* __restrict__ list,
    const int* __restrict__ offset, const int* __restrict__ count,
    float* __restrict__ out)
{
  const int m = blockIdx.x;
  const int d = threadIdx.x;       // 256 threads == DD
  const int off = offset[m];
  const int cnt = count[m];
  float acc = 0.f;
  int j = 0;
  for (; j + 4 <= cnt; j += 4) {
    const int i0 = list[off + j + 0];
    const int i1 = list[off + j + 1];
    const int i2 = list[off + j + 2];
    const int i3 = list[off + j + 3];
    const float w0 = w[i0], w1 = w[i1], w2 = w[i2], w3 = w[i3];
    const float v0 = value[(size_t)i0 * DD + d];
    const float v1 = value[(size_t)i1 * DD + d];
    const float v2 = value[(size_t)i2 * DD + d];
    const float v3 = value[(size_t)i3 * DD + d];
    acc = fmaf(w0, v0, acc);
    acc = fmaf(w1, v1, acc);
    acc = fmaf(w2, v2, acc);
    acc = fmaf(w3, v3, acc);
  }
  for (; j < cnt; ++j) {
    const int i = list[off + j];
    acc = fmaf(w[i], value[(size_t)i * DD + d], acc);
  }
  float x = acc + keys[(size_t)m * DD + d];
  float ss = x * x;
#pragma unroll
  for (int o = 1; o < 64; o <<= 1) ss += __shfl_xor(ss, o);
  __shared__ float wsum[4];
  if ((threadIdx.x & 63) == 0) wsum[threadIdx.x >> 6] = ss;
  __syncthreads();
  float tot = wsum[0] + wsum[1] + wsum[2] + wsum[3];
  float den = fmaxf(sqrtf(tot), 1e-12f);
  out[(size_t)m * DD + d] = x / den;
}

extern "C" void kernel_launch(void* const* d_in, const int* in_sizes, int n_in,
                              void* d_out, int out_size, void* d_ws, size_t ws_size,
                              hipStream_t stream)
{
  const float* keys  = (const float*)d_in[0];
  const float* query = (const float*)d_in[1];
  const float* value = (const float*)d_in[2];
  float* out = (float*)d_out;

  char* ws = (char*)d_ws;
  size_t o = 0;
  auto alloc = [&](size_t bytes) -> void* {
    void* p = ws + o;
    o += (bytes + 255) & ~(size_t)255;
    return p;
  };
  unsigned* colmax_enc = (unsigned*)alloc(MS * 4);
  int*      count      = (int*)     alloc(MS * 4);
  int*      offset     = (int*)     alloc(MS * 4);
  int*      assign     = (int*)     alloc((size_t)NQ * 4);
  float*    sval       = (float*)   alloc((size_t)NQ * 4);
  float*    wgt        = (float*)   alloc((size_t)NQ * 4);
  int*      pos        = (int*)     alloc((size_t)NQ * 4);
  int*      list       = (int*)     alloc((size_t)NQ * 4);

  hipMemsetAsync(colmax_enc, 0, MS * 4, stream);  // enc(x) > 0 for all finite x
  hipMemsetAsync(count, 0, MS * 4, stream);

  score_kernel <<<NQ / BQ, 256, 0, stream>>>(query, keys, assign, sval, colmax_enc);
  weight_kernel<<<NQ / 256, 256, 0, stream>>>(sval, assign, colmax_enc, wgt, pos, count);
  scan_kernel  <<<1, MS, 0, stream>>>(count, offset);
  fill_kernel  <<<NQ / 256, 256, 0, stream>>>(assign, pos, offset, list);
  update_kernel<<<MS, DD, 0, stream>>>(value, keys, wgt, list, offset, count, out);
}

// Round 3
// 494.801 us; speedup vs baseline: 1.2519x; 1.2519x over previous
//
#include <hip/hip_runtime.h>
#include <hip/hip_bf16.h>
#include <cstdint>
#include <cstddef>

#define NQ 131072   // queries
#define MS 512      // memory slots
#define DD 256      // feature dim

typedef _Float16 f16;
typedef _Float16 f16x8 __attribute__((ext_vector_type(8)));
typedef float f32x4 __attribute__((ext_vector_type(4)));

// ---- monotone float <-> uint encoding for atomicMax on f32 ----
__device__ __forceinline__ unsigned enc_f32(float x) {
  unsigned u = __float_as_uint(x);
  return (u & 0x80000000u) ? ~u : (u | 0x80000000u);
}
__device__ __forceinline__ float dec_f32(unsigned u) {
  unsigned b = (u & 0x80000000u) ? (u & 0x7FFFFFFFu) : ~u;
  return __uint_as_float(b);
}

// LDS swizzle for 64-B rows: XOR the 16B-slot index (bits 4-5) with (row ^ row>>2)&3.
// Involution; preserves 16B alignment; gives <=2-way bank conflicts for MFMA frag reads.
#define SW16(b) ((b) ^ (((((b) >> 6) ^ ((b) >> 8)) & 3) << 4))

// ======================= MFMA path =======================

// Split query f32 -> f16 hi/lo in blocked layout [qb(1024)][kq(8)][128][32]
__global__ __launch_bounds__(256) void qsplit_kernel(
    const float* __restrict__ q, f16* __restrict__ qhi, f16* __restrict__ qlo)
{
  union U4 { f16 h[4]; uint2 u; };
  const int bid = blockIdx.x, t = threadIdx.x;
#pragma unroll
  for (int u = 0; u < 8; ++u) {
    const int idx4 = bid * 2048 + u * 256 + t;       // 4096 blocks * 2048 = 8.39M float4
    const float4 v = reinterpret_cast<const float4*>(q)[idx4];
    const int e = idx4 * 4;
    const int r = e >> 8, k = e & 255;
    const int qb = r >> 7, rr = r & 127, kq = k >> 5, kc = k & 31;
    const size_t out = ((size_t)(qb * 8 + kq)) * 4096 + rr * 32 + kc;
    U4 uh, ul;
    float x;
    x = v.x; uh.h[0] = (f16)x; ul.h[0] = (f16)(x - (float)uh.h[0]);
    x = v.y; uh.h[1] = (f16)x; ul.h[1] = (f16)(x - (float)uh.h[1]);
    x = v.z; uh.h[2] = (f16)x; ul.h[2] = (f16)(x - (float)uh.h[2]);
    x = v.w; uh.h[3] = (f16)x; ul.h[3] = (f16)(x - (float)uh.h[3]);
    *reinterpret_cast<uint2*>(&qhi[out]) = uh.u;
    *reinterpret_cast<uint2*>(&qlo[out]) = ul.u;
  }
}

// Split keys f32 -> f16 hi/lo in blocked layout [sc(2)][kq(8)][256][32]
__global__ __launch_bounds__(256) void ksplit_kernel(
    const float* __restrict__ kk, f16* __restrict__ khi, f16* __restrict__ klo)
{
  union U4 { f16 h[4]; uint2 u; };
  const int bid = blockIdx.x, t = threadIdx.x;
#pragma unroll
  for (int u = 0; u < 2; ++u) {
    const int idx4 = bid * 512 + u * 256 + t;        // 64 blocks * 512 = 32768 float4
    const float4 v = reinterpret_cast<const float4*>(kk)[idx4];
    const int e = idx4 * 4;
    const int s = e >> 8, k = e & 255;
    const int sc = s >> 8, sr = s & 255, kq = k >> 5, kc = k & 31;
    const size_t out = ((size_t)(sc * 8 + kq)) * 8192 + sr * 32 + kc;
    U4 uh, ul;
    float x;
    x = v.x; uh.h[0] = (f16)x; ul.h[0] = (f16)(x - (float)uh.h[0]);
    x = v.y; uh.h[1] = (f16)x; ul.h[1] = (f16)(x - (float)uh.h[1]);
    x = v.z; uh.h[2] = (f16)x; ul.h[2] = (f16)(x - (float)uh.h[2]);
    x = v.w; uh.h[3] = (f16)x; ul.h[3] = (f16)(x - (float)uh.h[3]);
    *reinterpret_cast<uint2*>(&khi[out]) = uh.u;
    *reinterpret_cast<uint2*>(&klo[out]) = ul.u;
  }
}

// Score GEMM: block = 128 queries x 256 slots, 512 threads (8 waves 2x4),
// wave tile 64x64 (4x4 subtiles of 16x16), mfma_f32_16x16x32_f16, 3-term hi/lo.
// Fused row-argmax (u64 packed atomicMax) + col-max (u32 enc atomicMax).
__global__ __launch_bounds__(512) void score_mfma_kernel(
    const f16* __restrict__ qhi, const f16* __restrict__ qlo,
    const f16* __restrict__ khi, const f16* __restrict__ klo,
    unsigned long long* __restrict__ rowPacked,
    unsigned* __restrict__ colmax_enc)
{
  // LDS map (bytes): KH [256][32]f16 @0 (16384), KL @16384, QH [128][32] @32768 (8192), QL @40960
  __shared__ __align__(16) unsigned char LDS[49152];

  const int sc = blockIdx.x;      // slot half (0,1)
  const int qb = blockIdx.y;      // query block (0..1023)
  const int tid = threadIdx.x;
  const int l = tid & 63, wid = tid >> 6;
  const int wq = wid >> 2, ws = wid & 3;
  const int lg = l >> 4, ll = l & 15;
  const int kb = lg * 16;

  const char* kh_b = (const char*)khi + ((size_t)(sc * 8) << 14);
  const char* kl_b = (const char*)klo + ((size_t)(sc * 8) << 14);
  const char* qh_b = (const char*)qhi + (((size_t)qb * 8) << 13);
  const char* ql_b = (const char*)qlo + (((size_t)qb * 8) << 13);

  f32x4 acc[4][4];
#pragma unroll
  for (int i = 0; i < 4; ++i)
#pragma unroll
    for (int j = 0; j < 4; ++j) acc[i][j] = (f32x4){0.f, 0.f, 0.f, 0.f};

  uint4 pf[6];
  auto load = [&](int kq) {
    const char* skh = kh_b + ((size_t)kq << 14);
    const char* skl = kl_b + ((size_t)kq << 14);
    const char* sqh = qh_b + ((size_t)kq << 13);
    const char* sql = ql_b + ((size_t)kq << 13);
    pf[0] = *(const uint4*)(skh + tid * 16);
    pf[1] = *(const uint4*)(skh + 8192 + tid * 16);
    pf[2] = *(const uint4*)(skl + tid * 16);
    pf[3] = *(const uint4*)(skl + 8192 + tid * 16);
    pf[4] = *(const uint4*)(sqh + tid * 16);
    pf[5] = *(const uint4*)(sql + tid * 16);
  };

  load(0);
  for (int kq = 0; kq < 8; ++kq) {
    __syncthreads();   // prior compute done reading LDS
    *(uint4*)&LDS[SW16(0     + tid * 16)] = pf[0];
    *(uint4*)&LDS[SW16(8192  + tid * 16)] = pf[1];
    *(uint4*)&LDS[SW16(16384 + tid * 16)] = pf[2];
    *(uint4*)&LDS[SW16(24576 + tid * 16)] = pf[3];
    *(uint4*)&LDS[SW16(32768 + tid * 16)] = pf[4];
    *(uint4*)&LDS[SW16(40960 + tid * 16)] = pf[5];
    __syncthreads();
    if (kq < 7) load(kq + 1);   // prefetch next chunk; latency hides under MFMA

    f16x8 ah[4], al[4], bh[4], bl[4];
#pragma unroll
    for (int i = 0; i < 4; ++i) {
      const int r = wq * 64 + i * 16 + ll;
      ah[i] = *(const f16x8*)&LDS[SW16(32768 + r * 64 + kb)];
      al[i] = *(const f16x8*)&LDS[SW16(40960 + r * 64 + kb)];
    }
#pragma unroll
    for (int j = 0; j < 4; ++j) {
      const int s = ws * 64 + j * 16 + ll;
      bh[j] = *(const f16x8*)&LDS[SW16(s * 64 + kb)];
      bl[j] = *(const f16x8*)&LDS[SW16(16384 + s * 64 + kb)];
    }
#pragma unroll
    for (int i = 0; i < 4; ++i)
#pragma unroll
      for (int j = 0; j < 4; ++j) {
        f32x4 c = acc[i][j];
        c = __builtin_amdgcn_mfma_f32_16x16x32_f16(ah[i], bl[j], c, 0, 0, 0);
        c = __builtin_amdgcn_mfma_f32_16x16x32_f16(al[i], bh[j], c, 0, 0, 0);
        c = __builtin_amdgcn_mfma_f32_16x16x32_f16(ah[i], bh[j], c, 0, 0, 0);
        acc[i][j] = c;
      }
  }

  // ---- reductions ----
  // C layout (m89-verified): elem v of acc[i][j]: row = wq*64+i*16+(l>>4)*4+v,
  //                          col(within 256) = ws*64+j*16+(l&15)
  __syncthreads();   // all waves done reading LDS; overlay reductions on Q area
  unsigned long long* redRow = (unsigned long long*)(LDS + 32768);  // [128][4ws]
  float* redCol = (float*)(LDS + 36864);                            // [256][2wq]

#pragma unroll
  for (int i = 0; i < 4; ++i)
#pragma unroll
    for (int v = 0; v < 4; ++v) {
      float bv = acc[i][0][v];
      int bc = ws * 64 + ll;
#pragma unroll
      for (int j = 1; j < 4; ++j) {
        const float x = acc[i][j][v];
        const int c = ws * 64 + j * 16 + ll;
        if (x > bv) { bv = x; bc = c; }
      }
      const int gidx = sc * 256 + bc;
      unsigned long long p =
          ((unsigned long long)enc_f32(bv) << 32) | (unsigned)(~(unsigned)gidx);
#pragma unroll
      for (int m = 1; m < 16; m <<= 1) {
        const unsigned long long q = __shfl_xor(p, m);
        if (q > p) p = q;
      }
      if (ll == 0) redRow[(wq * 64 + i * 16 + lg * 4 + v) * 4 + ws] = p;
    }

#pragma unroll
  for (int j = 0; j < 4; ++j) {
    float m = acc[0][j][0];
#pragma unroll
    for (int i = 0; i < 4; ++i)
#pragma unroll
      for (int v = 0; v < 4; ++v) m = fmaxf(m, acc[i][j][v]);
    m = fmaxf(m, __shfl_xor(m, 16));
    m = fmaxf(m, __shfl_xor(m, 32));
    if (l < 16) redCol[(ws * 64 + j * 16 + l) * 2 + wq] = m;
  }

  __syncthreads();
  if (tid < 128) {
    unsigned long long p = redRow[tid * 4];
#pragma unroll
    for (int w = 1; w < 4; ++w) {
      const unsigned long long q = redRow[tid * 4 + w];
      if (q > p) p = q;
    }
    atomicMax(&rowPacked[(size_t)qb * 128 + tid], p);
  }
  if (tid < 256) {
    const float v = fmaxf(redCol[tid * 2], redCol[tid * 2 + 1]);
    atomicMax(&colmax_enc[sc * 256 + tid], enc_f32(v));
  }
}

// ---- weights + per-slot counts (MFMA path: reads rowPacked) ----
__global__ void weight2_kernel(const unsigned long long* __restrict__ rowPacked,
                               const unsigned* __restrict__ colmax_enc,
                               float* __restrict__ w, int* __restrict__ assign,
                               int* __restrict__ pos, int* __restrict__ count)
{
  const int i = blockIdx.x * blockDim.x + threadIdx.x;
  if (i >= NQ) return;
  const unsigned long long p = rowPacked[i];
  const int a = (int)(~(unsigned)(p & 0xFFFFFFFFull));
  const float sv = dec_f32((unsigned)(p >> 32));
  const float cm = dec_f32(colmax_enc[a]);
  w[i] = expf(sv - cm);
  assign[i] = a;
  pos[i] = atomicAdd(&count[a], 1);
}

// ======================= fallback path (round-1, verified) =======================
#define BQ 128
#define BM 128
#define DC 32
#define PAD 132

__global__ __launch_bounds__(256) void score_kernel(
    const float* __restrict__ query, const float* __restrict__ keys,
    int* __restrict__ assign_out, float* __restrict__ sval_out,
    unsigned* __restrict__ colmax_enc)
{
  __shared__ float Qs[DC][PAD];
  __shared__ float Ks[DC][PAD];
  __shared__ float redV[BQ * 16];
  __shared__ int   redI[BQ * 16];

  const int tid = threadIdx.x;
  const int ty = tid >> 4;
  const int tx = tid & 15;
  const int q0 = blockIdx.x * BQ;

  float bestV = -3.4e38f;
  int   bestI = 0;

  for (int mc = 0; mc < MS / BM; ++mc) {
    float acc[8][8];
#pragma unroll
    for (int i = 0; i < 8; ++i)
#pragma unroll
      for (int j = 0; j < 8; ++j) acc[i][j] = 0.f;

    for (int dc = 0; dc < DD; dc += DC) {
      __syncthreads();
#pragma unroll
      for (int it = 0; it < 4; ++it) {
        const int r = (tid >> 3) + it * 32;
        const int d = (tid & 7) * 4;
        const float4 qv = *reinterpret_cast<const float4*>(
            &query[(size_t)(q0 + r) * DD + dc + d]);
        Qs[d + 0][r] = qv.x; Qs[d + 1][r] = qv.y;
        Qs[d + 2][r] = qv.z; Qs[d + 3][r] = qv.w;
        const float4 kv = *reinterpret_cast<const float4*>(
            &keys[(size_t)(mc * BM + r) * DD + dc + d]);
        Ks[d + 0][r] = kv.x; Ks[d + 1][r] = kv.y;
        Ks[d + 2][r] = kv.z; Ks[d + 3][r] = kv.w;
      }
      __syncthreads();
#pragma unroll
      for (int d = 0; d < DC; ++d) {
        float a[8], b[8];
        *reinterpret_cast<float4*>(&a[0]) = *reinterpret_cast<const float4*>(&Qs[d][ty * 8]);
        *reinterpret_cast<float4*>(&a[4]) = *reinterpret_cast<const float4*>(&Qs[d][ty * 8 + 4]);
        *reinterpret_cast<float4*>(&b[0]) = *reinterpret_cast<const float4*>(&Ks[d][tx * 8]);
        *reinterpret_cast<float4*>(&b[4]) = *reinterpret_cast<const float4*>(&Ks[d][tx * 8 + 4]);
#pragma unroll
        for (int i = 0; i < 8; ++i)
#pragma unroll
          for (int j = 0; j < 8; ++j)
            acc[i][j] = fmaf(a[i], b[j], acc[i][j]);
      }
    }

    __syncthreads();
#pragma unroll
    for (int i = 0; i < 8; ++i) {
      float v = acc[i][0]; int jj = 0;
#pragma unroll
      for (int j = 1; j < 8; ++j)
        if (acc[i][j] > v) { v = acc[i][j]; jj = j; }
      redV[(ty * 8 + i) * 16 + tx] = v;
      redI[(ty * 8 + i) * 16 + tx] = mc * BM + tx * 8 + jj;
    }
    __syncthreads();
    if (tid < BQ) {
#pragma unroll
      for (int t = 0; t < 16; ++t) {
        float v = redV[tid * 16 + t];
        if (v > bestV) { bestV = v; bestI = redI[tid * 16 + t]; }
      }
    }
    __syncthreads();
#pragma unroll
    for (int j = 0; j < 8; ++j) {
      float v = acc[0][j];
#pragma unroll
      for (int i = 1; i < 8; ++i) v = fmaxf(v, acc[i][j]);
      redV[(tx * 8 + j) * 16 + ty] = v;
    }
    __syncthreads();
    if (tid < BM) {
      float v = redV[tid * 16];
#pragma unroll
      for (int t = 1; t < 16; ++t) v = fmaxf(v, redV[tid * 16 + t]);
      atomicMax(&colmax_enc[mc * BM + tid], enc_f32(v));
    }
  }

  if (tid < BQ) {
    assign_out[q0 + tid] = bestI;
    sval_out[q0 + tid]   = bestV;
  }
}

__global__ void weight_kernel(const float* __restrict__ sval,
                              const int* __restrict__ assign,
                              const unsigned* __restrict__ colmax_enc,
                              float* __restrict__ w,
                              int* __restrict__ pos,
                              int* __restrict__ count)
{
  int i = blockIdx.x * blockDim.x + threadIdx.x;
  if (i >= NQ) return;
  int a = assign[i];
  float cm = dec_f32(colmax_enc[a]);
  w[i] = expf(sval[i] - cm);
  pos[i] = atomicAdd(&count[a], 1);
}

// ======================= shared tail kernels =======================

__global__ void scan_kernel(const int* __restrict__ count, int* __restrict__ offset)
{
  __shared__ int s[MS];
  int t = threadIdx.x;
  int c = count[t];
  s[t] = c;
  __syncthreads();
  for (int off = 1; off < MS; off <<= 1) {
    int v = (t >= off) ? s[t - off] : 0;
    __syncthreads();
    s[t] += v;
    __syncthreads();
  }
  offset[t] = s[t] - c;
}

__global__ void fill_kernel(const int* __restrict__ assign,
                            const int* __restrict__ pos,
                            const int* __restrict__ offset,
                            int* __restrict__ list)
{
  int i = blockIdx.x * blockDim.x + threadIdx.x;
  if (i >= NQ) return;
  int a = assign[i];
  list[offset[a] + pos[i]] = i;
}

__global__ __launch_bounds__(256) void update_kernel(
    const float* __restrict__ value, const float* __restrict__ keys,
    const float* __restrict__ w, const int* __restrict__ list,
    const int* __restrict__ offset, const int* __restrict__ count,
    float* __restrict__ out)
{
  const int m = blockIdx.x;
  const int d = threadIdx.x;
  const int off = offset[m];
  const int cnt = count[m];
  float acc = 0.f;
  int j = 0;
  for (; j + 4 <= cnt; j += 4) {
    const int i0 = list[off + j + 0];
    const int i1 = list[off + j + 1];
    const int i2 = list[off + j + 2];
    const int i3 = list[off + j + 3];
    const float w0 = w[i0], w1 = w[i1], w2 = w[i2], w3 = w[i3];
    const float v0 = value[(size_t)i0 * DD + d];
    const float v1 = value[(size_t)i1 * DD + d];
    const float v2 = value[(size_t)i2 * DD + d];
    const float v3 = value[(size_t)i3 * DD + d];
    acc = fmaf(w0, v0, acc);
    acc = fmaf(w1, v1, acc);
    acc = fmaf(w2, v2, acc);
    acc = fmaf(w3, v3, acc);
  }
  for (; j < cnt; ++j) {
    const int i = list[off + j];
    acc = fmaf(w[i], value[(size_t)i * DD + d], acc);
  }
  float x = acc + keys[(size_t)m * DD + d];
  float ss = x * x;
#pragma unroll
  for (int o = 1; o < 64; o <<= 1) ss += __shfl_xor(ss, o);
  __shared__ float wsum[4];
  if ((threadIdx.x & 63) == 0) wsum[threadIdx.x >> 6] = ss;
  __syncthreads();
  float tot = wsum[0] + wsum[1] + wsum[2] + wsum[3];
  float den = fmaxf(sqrtf(tot), 1e-12f);
  out[(size_t)m * DD + d] = x / den;
}

// ======================= launcher =======================

extern "C" void kernel_launch(void* const* d_in, const int* in_sizes, int n_in,
                              void* d_out, int out_size, void* d_ws, size_t ws_size,
                              hipStream_t stream)
{
  const float* keys  = (const float*)d_in[0];
  const float* query = (const float*)d_in[1];
  const float* value = (const float*)d_in[2];
  float* out = (float*)d_out;

  char* ws = (char*)d_ws;
  size_t o = 0;
  auto alloc = [&](size_t bytes) -> void* {
    void* p = ws + o;
    o += (bytes + 255) & ~(size_t)255;
    return p;
  };

  // --- MFMA-path layout ---
  f16* qhi = (f16*)alloc((size_t)NQ * DD * 2);
  f16* qlo = (f16*)alloc((size_t)NQ * DD * 2);
  f16* khi = (f16*)alloc((size_t)MS * DD * 2);
  f16* klo = (f16*)alloc((size_t)MS * DD * 2);
  unsigned long long* rowPacked = (unsigned long long*)alloc((size_t)NQ * 8);
  unsigned* colmax_enc = (unsigned*)alloc(MS * 4);
  int* count  = (int*)alloc(MS * 4);
  int* offset = (int*)alloc(MS * 4);
  int* assign = (int*)alloc((size_t)NQ * 4);
  float* wgt  = (float*)alloc((size_t)NQ * 4);
  int* pos    = (int*)alloc((size_t)NQ * 4);
  int* list   = (int*)alloc((size_t)NQ * 4);
  const size_t mfma_need = o;

  if (ws_size >= mfma_need) {
    hipMemsetAsync(rowPacked, 0, (size_t)NQ * 8, stream);
    hipMemsetAsync(colmax_enc, 0, MS * 4, stream);
    hipMemsetAsync(count, 0, MS * 4, stream);

    ksplit_kernel<<<64, 256, 0, stream>>>(keys, khi, klo);
    qsplit_kernel<<<4096, 256, 0, stream>>>(query, qhi, qlo);
    score_mfma_kernel<<<dim3(2, 1024), 512, 0, stream>>>(qhi, qlo, khi, klo,
                                                         rowPacked, colmax_enc);
    weight2_kernel<<<NQ / 256, 256, 0, stream>>>(rowPacked, colmax_enc,
                                                 wgt, assign, pos, count);
    scan_kernel<<<1, MS, 0, stream>>>(count, offset);
    fill_kernel<<<NQ / 256, 256, 0, stream>>>(assign, pos, offset, list);
    update_kernel<<<MS, DD, 0, stream>>>(value, keys, wgt, list, offset, count, out);
  } else {
    // --- fallback: round-1 verified fp32-VALU path ---
    size_t o2 = 0;
    auto alloc2 = [&](size_t bytes) -> void* {
      void* p = ws + o2;
      o2 += (bytes + 255) & ~(size_t)255;
      return p;
    };
    unsigned* colmax2 = (unsigned*)alloc2(MS * 4);
    int* count2  = (int*)alloc2(MS * 4);
    int* offset2 = (int*)alloc2(MS * 4);
    int* assign2 = (int*)alloc2((size_t)NQ * 4);
    float* sval2 = (float*)alloc2((size_t)NQ * 4);
    float* wgt2  = (float*)alloc2((size_t)NQ * 4);
    int* pos2    = (int*)alloc2((size_t)NQ * 4);
    int* list2   = (int*)alloc2((size_t)NQ * 4);

    hipMemsetAsync(colmax2, 0, MS * 4, stream);
    hipMemsetAsync(count2, 0, MS * 4, stream);

    score_kernel<<<NQ / BQ, 256, 0, stream>>>(query, keys, assign2, sval2, colmax2);
    weight_kernel<<<NQ / 256, 256, 0, stream>>>(sval2, assign2, colmax2, wgt2, pos2, count2);
    scan_kernel<<<1, MS, 0, stream>>>(count2, offset2);
    fill_kernel<<<NQ / 256, 256, 0, stream>>>(assign2, pos2, offset2, list2);
    update_kernel<<<MS, DD, 0, stream>>>(value, keys, wgt2, list2, offset2, count2, out);
  }
}

// Round 4
// 290.788 us; speedup vs baseline: 2.1302x; 1.7016x over previous
//
#include <hip/hip_runtime.h>
#include <hip/hip_bf16.h>
#include <cstdint>
#include <cstddef>

#define NQ 131072   // queries
#define MS 512      // memory slots
#define DD 256      // feature dim

typedef _Float16 f16;
typedef _Float16 f16x8 __attribute__((ext_vector_type(8)));
typedef float f32x4 __attribute__((ext_vector_type(4)));

// ---- monotone float <-> uint encoding for atomicMax on f32 ----
__device__ __forceinline__ unsigned enc_f32(float x) {
  unsigned u = __float_as_uint(x);
  return (u & 0x80000000u) ? ~u : (u | 0x80000000u);
}
__device__ __forceinline__ float dec_f32(unsigned u) {
  unsigned b = (u & 0x80000000u) ? (u & 0x7FFFFFFFu) : ~u;
  return __uint_as_float(b);
}

// exact 2-term f16 split of a float4
__device__ __forceinline__ void cvt4(const float4 v, uint2& uhi, uint2& ulo) {
  union U { f16 h[4]; uint2 u; } a, b;
  float x;
  x = v.x; a.h[0] = (f16)x; b.h[0] = (f16)(x - (float)a.h[0]);
  x = v.y; a.h[1] = (f16)x; b.h[1] = (f16)(x - (float)a.h[1]);
  x = v.z; a.h[2] = (f16)x; b.h[2] = (f16)(x - (float)a.h[2]);
  x = v.w; a.h[3] = (f16)x; b.h[3] = (f16)(x - (float)a.h[3]);
  uhi = a.u; ulo = b.u;
}

// ======================= MFMA path =======================
// LDS byte map (region-blocked, 32B pad per region => region stride == 8 banks mod 32):
//   KH [4][256*16+32] @ 0      (4*4128 = 16512)
//   KL                @ 16512
//   QH [4][128*16+32] @ 33024  (4*2080 = 8320)
//   QL                @ 41344
//   total 49664 B
#define KH_OFF 0
#define KL_OFF 16512
#define QH_OFF 33024
#define QL_OFF 41344
#define KSTR 4128
#define QSTR 2080

// Score GEMM: block = 128 queries x 256 slots, 512 threads (8 waves 2x4),
// wave tile 64x64 (4x4 subtiles of 16x16), mfma_f32_16x16x32_f16, 3-term hi/lo split
// computed in-register from f32 inputs. Fused row-argmax (packed u64 atomicMax)
// + col-max (encoded u32 atomicMax).
__global__ __launch_bounds__(512, 1) void score_mfma_kernel(
    const float* __restrict__ query, const float* __restrict__ keys,
    unsigned long long* __restrict__ rowPacked,
    unsigned* __restrict__ colmax_enc)
{
  __shared__ __align__(16) unsigned char LDS[49664];

  const int sc = blockIdx.x;      // slot half (0,1)
  const int qb = blockIdx.y;      // query block (0..1023)
  const int tid = threadIdx.x;
  const int l = tid & 63, wid = tid >> 6;
  const int wq = wid >> 2, ws = wid & 3;
  const int lg = l >> 4, ll = l & 15;
  const int q0 = qb * 128;

  f32x4 acc[4][4];
#pragma unroll
  for (int i = 0; i < 4; ++i)
#pragma unroll
    for (int j = 0; j < 4; ++j) acc[i][j] = (f32x4){0.f, 0.f, 0.f, 0.f};

  float4 pf[6];
  auto load = [&](int kq) {
    const int kofs = kq * 32;
#pragma unroll
    for (int u = 0; u < 4; ++u) {           // K tile: 256 rows x 32 cols f32
      const int idx = u * 512 + tid;
      const int r = idx >> 3, c4 = idx & 7;
      pf[u] = *(const float4*)&keys[(size_t)(sc * 256 + r) * DD + kofs + c4 * 4];
    }
#pragma unroll
    for (int u = 0; u < 2; ++u) {           // Q tile: 128 rows x 32 cols f32
      const int idx = u * 512 + tid;
      const int r = idx >> 3, c4 = idx & 7;
      pf[4 + u] = *(const float4*)&query[(size_t)(q0 + r) * DD + kofs + c4 * 4];
    }
  };

  load(0);
  for (int kq = 0; kq < 8; ++kq) {
    __syncthreads();   // prior compute done reading LDS
    // convert + stage current chunk
#pragma unroll
    for (int u = 0; u < 4; ++u) {
      const int idx = u * 512 + tid;
      const int r = idx >> 3, c4 = idx & 7, rg = c4 >> 1, hf = c4 & 1;
      uint2 uh, ul;
      cvt4(pf[u], uh, ul);
      const int off = rg * KSTR + r * 16 + hf * 8;
      *(uint2*)&LDS[KH_OFF + off] = uh;
      *(uint2*)&LDS[KL_OFF + off] = ul;
    }
#pragma unroll
    for (int u = 0; u < 2; ++u) {
      const int idx = u * 512 + tid;
      const int r = idx >> 3, c4 = idx & 7, rg = c4 >> 1, hf = c4 & 1;
      uint2 uh, ul;
      cvt4(pf[4 + u], uh, ul);
      const int off = rg * QSTR + r * 16 + hf * 8;
      *(uint2*)&LDS[QH_OFF + off] = uh;
      *(uint2*)&LDS[QL_OFF + off] = ul;
    }
    __syncthreads();
    if (kq < 7) load(kq + 1);   // fire-and-forget prefetch; consumed next iter

    f16x8 ah[4], al[4], bh[4], bl[4];
#pragma unroll
    for (int i = 0; i < 4; ++i) {
      const int r = wq * 64 + i * 16 + ll;
      ah[i] = *(const f16x8*)&LDS[QH_OFF + lg * QSTR + r * 16];
      al[i] = *(const f16x8*)&LDS[QL_OFF + lg * QSTR + r * 16];
    }
#pragma unroll
    for (int j = 0; j < 4; ++j) {
      const int s = ws * 64 + j * 16 + ll;
      bh[j] = *(const f16x8*)&LDS[KH_OFF + lg * KSTR + s * 16];
      bl[j] = *(const f16x8*)&LDS[KL_OFF + lg * KSTR + s * 16];
    }
#pragma unroll
    for (int i = 0; i < 4; ++i)
#pragma unroll
      for (int j = 0; j < 4; ++j) {
        f32x4 c = acc[i][j];
        c = __builtin_amdgcn_mfma_f32_16x16x32_f16(ah[i], bl[j], c, 0, 0, 0);
        c = __builtin_amdgcn_mfma_f32_16x16x32_f16(al[i], bh[j], c, 0, 0, 0);
        c = __builtin_amdgcn_mfma_f32_16x16x32_f16(ah[i], bh[j], c, 0, 0, 0);
        acc[i][j] = c;
      }
  }

  // ---- reductions ----
  // C layout (verified R3 end-to-end): elem v of acc[i][j]:
  //   row = wq*64 + i*16 + lg*4 + v, col(within 256) = ws*64 + j*16 + ll
  __syncthreads();   // all waves done reading LDS; overlay reductions
  unsigned long long* redRow = (unsigned long long*)(LDS);        // [128][4]
  float* redCol = (float*)(LDS + 4096);                           // [256][2]

#pragma unroll
  for (int i = 0; i < 4; ++i)
#pragma unroll
    for (int v = 0; v < 4; ++v) {
      float bv = acc[i][0][v];
      int bc = ws * 64 + ll;
#pragma unroll
      for (int j = 1; j < 4; ++j) {
        const float x = acc[i][j][v];
        const int c = ws * 64 + j * 16 + ll;
        if (x > bv) { bv = x; bc = c; }
      }
      const int gidx = sc * 256 + bc;
      unsigned long long p =
          ((unsigned long long)enc_f32(bv) << 32) | (unsigned)(~(unsigned)gidx);
#pragma unroll
      for (int m = 1; m < 16; m <<= 1) {
        const unsigned long long q = __shfl_xor(p, m);
        if (q > p) p = q;
      }
      if (ll == 0) redRow[(wq * 64 + i * 16 + lg * 4 + v) * 4 + ws] = p;
    }

#pragma unroll
  for (int j = 0; j < 4; ++j) {
    float m = acc[0][j][0];
#pragma unroll
    for (int i = 0; i < 4; ++i)
#pragma unroll
      for (int v = 0; v < 4; ++v) m = fmaxf(m, acc[i][j][v]);
    m = fmaxf(m, __shfl_xor(m, 16));
    m = fmaxf(m, __shfl_xor(m, 32));
    if (l < 16) redCol[(ws * 64 + j * 16 + l) * 2 + wq] = m;
  }

  __syncthreads();
  if (tid < 128) {
    unsigned long long p = redRow[tid * 4];
#pragma unroll
    for (int w = 1; w < 4; ++w) {
      const unsigned long long q = redRow[tid * 4 + w];
      if (q > p) p = q;
    }
    atomicMax(&rowPacked[(size_t)qb * 128 + tid], p);
  }
  if (tid < 256) {
    const float v = fmaxf(redCol[tid * 2], redCol[tid * 2 + 1]);
    atomicMax(&colmax_enc[sc * 256 + tid], enc_f32(v));
  }
}

// ---- weights + per-slot counts (MFMA path: reads rowPacked) ----
__global__ void weight2_kernel(const unsigned long long* __restrict__ rowPacked,
                               const unsigned* __restrict__ colmax_enc,
                               float* __restrict__ w, int* __restrict__ assign,
                               int* __restrict__ pos, int* __restrict__ count)
{
  const int i = blockIdx.x * blockDim.x + threadIdx.x;
  if (i >= NQ) return;
  const unsigned long long p = rowPacked[i];
  const int a = (int)(~(unsigned)(p & 0xFFFFFFFFull));
  const float sv = dec_f32((unsigned)(p >> 32));
  const float cm = dec_f32(colmax_enc[a]);
  w[i] = expf(sv - cm);
  assign[i] = a;
  pos[i] = atomicAdd(&count[a], 1);
}

// ======================= fallback path (round-1, verified) =======================
#define BQ 128
#define BM 128
#define DC 32
#define PAD 132

__global__ __launch_bounds__(256) void score_kernel(
    const float* __restrict__ query, const float* __restrict__ keys,
    int* __restrict__ assign_out, float* __restrict__ sval_out,
    unsigned* __restrict__ colmax_enc)
{
  __shared__ float Qs[DC][PAD];
  __shared__ float Ks[DC][PAD];
  __shared__ float redV[BQ * 16];
  __shared__ int   redI[BQ * 16];

  const int tid = threadIdx.x;
  const int ty = tid >> 4;
  const int tx = tid & 15;
  const int q0 = blockIdx.x * BQ;

  float bestV = -3.4e38f;
  int   bestI = 0;

  for (int mc = 0; mc < MS / BM; ++mc) {
    float acc[8][8];
#pragma unroll
    for (int i = 0; i < 8; ++i)
#pragma unroll
      for (int j = 0; j < 8; ++j) acc[i][j] = 0.f;

    for (int dc = 0; dc < DD; dc += DC) {
      __syncthreads();
#pragma unroll
      for (int it = 0; it < 4; ++it) {
        const int r = (tid >> 3) + it * 32;
        const int d = (tid & 7) * 4;
        const float4 qv = *reinterpret_cast<const float4*>(
            &query[(size_t)(q0 + r) * DD + dc + d]);
        Qs[d + 0][r] = qv.x; Qs[d + 1][r] = qv.y;
        Qs[d + 2][r] = qv.z; Qs[d + 3][r] = qv.w;
        const float4 kv = *reinterpret_cast<const float4*>(
            &keys[(size_t)(mc * BM + r) * DD + dc + d]);
        Ks[d + 0][r] = kv.x; Ks[d + 1][r] = kv.y;
        Ks[d + 2][r] = kv.z; Ks[d + 3][r] = kv.w;
      }
      __syncthreads();
#pragma unroll
      for (int d = 0; d < DC; ++d) {
        float a[8], b[8];
        *reinterpret_cast<float4*>(&a[0]) = *reinterpret_cast<const float4*>(&Qs[d][ty * 8]);
        *reinterpret_cast<float4*>(&a[4]) = *reinterpret_cast<const float4*>(&Qs[d][ty * 8 + 4]);
        *reinterpret_cast<float4*>(&b[0]) = *reinterpret_cast<const float4*>(&Ks[d][tx * 8]);
        *reinterpret_cast<float4*>(&b[4]) = *reinterpret_cast<const float4*>(&Ks[d][tx * 8 + 4]);
#pragma unroll
        for (int i = 0; i < 8; ++i)
#pragma unroll
          for (int j = 0; j < 8; ++j)
            acc[i][j] = fmaf(a[i], b[j], acc[i][j]);
      }
    }

    __syncthreads();
#pragma unroll
    for (int i = 0; i < 8; ++i) {
      float v = acc[i][0]; int jj = 0;
#pragma unroll
      for (int j = 1; j < 8; ++j)
        if (acc[i][j] > v) { v = acc[i][j]; jj = j; }
      redV[(ty * 8 + i) * 16 + tx] = v;
      redI[(ty * 8 + i) * 16 + tx] = mc * BM + tx * 8 + jj;
    }
    __syncthreads();
    if (tid < BQ) {
#pragma unroll
      for (int t = 0; t < 16; ++t) {
        float v = redV[tid * 16 + t];
        if (v > bestV) { bestV = v; bestI = redI[tid * 16 + t]; }
      }
    }
    __syncthreads();
#pragma unroll
    for (int j = 0; j < 8; ++j) {
      float v = acc[0][j];
#pragma unroll
      for (int i = 1; i < 8; ++i) v = fmaxf(v, acc[i][j]);
      redV[(tx * 8 + j) * 16 + ty] = v;
    }
    __syncthreads();
    if (tid < BM) {
      float v = redV[tid * 16];
#pragma unroll
      for (int t = 1; t < 16; ++t) v = fmaxf(v, redV[tid * 16 + t]);
      atomicMax(&colmax_enc[mc * BM + tid], enc_f32(v));
    }
  }

  if (tid < BQ) {
    assign_out[q0 + tid] = bestI;
    sval_out[q0 + tid]   = bestV;
  }
}

__global__ void weight_kernel(const float* __restrict__ sval,
                              const int* __restrict__ assign,
                              const unsigned* __restrict__ colmax_enc,
                              float* __restrict__ w,
                              int* __restrict__ pos,
                              int* __restrict__ count)
{
  int i = blockIdx.x * blockDim.x + threadIdx.x;
  if (i >= NQ) return;
  int a = assign[i];
  float cm = dec_f32(colmax_enc[a]);
  w[i] = expf(sval[i] - cm);
  pos[i] = atomicAdd(&count[a], 1);
}

// ======================= shared tail kernels =======================

__global__ void scan_kernel(const int* __restrict__ count, int* __restrict__ offset)
{
  __shared__ int s[MS];
  int t = threadIdx.x;
  int c = count[t];
  s[t] = c;
  __syncthreads();
  for (int off = 1; off < MS; off <<= 1) {
    int v = (t >= off) ? s[t - off] : 0;
    __syncthreads();
    s[t] += v;
    __syncthreads();
  }
  offset[t] = s[t] - c;
}

__global__ void fill_kernel(const int* __restrict__ assign,
                            const int* __restrict__ pos,
                            const int* __restrict__ offset,
                            int* __restrict__ list)
{
  int i = blockIdx.x * blockDim.x + threadIdx.x;
  if (i >= NQ) return;
  int a = assign[i];
  list[offset[a] + pos[i]] = i;
}

__global__ __launch_bounds__(256) void update_kernel(
    const float* __restrict__ value, const float* __restrict__ keys,
    const float* __restrict__ w, const int* __restrict__ list,
    const int* __restrict__ offset, const int* __restrict__ count,
    float* __restrict__ out)
{
  const int m = blockIdx.x;
  const int d = threadIdx.x;
  const int off = offset[m];
  const int cnt = count[m];
  float acc = 0.f;
  int j = 0;
  for (; j + 4 <= cnt; j += 4) {
    const int i0 = list[off + j + 0];
    const int i1 = list[off + j + 1];
    const int i2 = list[off + j + 2];
    const int i3 = list[off + j + 3];
    const float w0 = w[i0], w1 = w[i1], w2 = w[i2], w3 = w[i3];
    const float v0 = value[(size_t)i0 * DD + d];
    const float v1 = value[(size_t)i1 * DD + d];
    const float v2 = value[(size_t)i2 * DD + d];
    const float v3 = value[(size_t)i3 * DD + d];
    acc = fmaf(w0, v0, acc);
    acc = fmaf(w1, v1, acc);
    acc = fmaf(w2, v2, acc);
    acc = fmaf(w3, v3, acc);
  }
  for (; j < cnt; ++j) {
    const int i = list[off + j];
    acc = fmaf(w[i], value[(size_t)i * DD + d], acc);
  }
  float x = acc + keys[(size_t)m * DD + d];
  float ss = x * x;
#pragma unroll
  for (int o = 1; o < 64; o <<= 1) ss += __shfl_xor(ss, o);
  __shared__ float wsum[4];
  if ((threadIdx.x & 63) == 0) wsum[threadIdx.x >> 6] = ss;
  __syncthreads();
  float tot = wsum[0] + wsum[1] + wsum[2] + wsum[3];
  float den = fmaxf(sqrtf(tot), 1e-12f);
  out[(size_t)m * DD + d] = x / den;
}

// ======================= launcher =======================

extern "C" void kernel_launch(void* const* d_in, const int* in_sizes, int n_in,
                              void* d_out, int out_size, void* d_ws, size_t ws_size,
                              hipStream_t stream)
{
  const float* keys  = (const float*)d_in[0];
  const float* query = (const float*)d_in[1];
  const float* value = (const float*)d_in[2];
  float* out = (float*)d_out;

  char* ws = (char*)d_ws;
  size_t o = 0;
  auto alloc = [&](size_t bytes) -> void* {
    void* p = ws + o;
    o += (bytes + 255) & ~(size_t)255;
    return p;
  };

  unsigned long long* rowPacked = (unsigned long long*)alloc((size_t)NQ * 8);
  unsigned* colmax_enc = (unsigned*)alloc(MS * 4);
  int* count  = (int*)alloc(MS * 4);
  int* offset = (int*)alloc(MS * 4);
  int* assign = (int*)alloc((size_t)NQ * 4);
  float* wgt  = (float*)alloc((size_t)NQ * 4);
  int* pos    = (int*)alloc((size_t)NQ * 4);
  int* list   = (int*)alloc((size_t)NQ * 4);
  const size_t mfma_need = o;

  if (ws_size >= mfma_need) {
    hipMemsetAsync(rowPacked, 0, (size_t)NQ * 8, stream);
    hipMemsetAsync(colmax_enc, 0, MS * 4, stream);
    hipMemsetAsync(count, 0, MS * 4, stream);

    score_mfma_kernel<<<dim3(2, 1024), 512, 0, stream>>>(query, keys,
                                                         rowPacked, colmax_enc);
    weight2_kernel<<<NQ / 256, 256, 0, stream>>>(rowPacked, colmax_enc,
                                                 wgt, assign, pos, count);
    scan_kernel<<<1, MS, 0, stream>>>(count, offset);
    fill_kernel<<<NQ / 256, 256, 0, stream>>>(assign, pos, offset, list);
    update_kernel<<<MS, DD, 0, stream>>>(value, keys, wgt, list, offset, count, out);
  } else {
    // --- fallback: round-1 verified fp32-VALU path ---
    size_t o2 = 0;
    auto alloc2 = [&](size_t bytes) -> void* {
      void* p = ws + o2;
      o2 += (bytes + 255) & ~(size_t)255;
      return p;
    };
    unsigned* colmax2 = (unsigned*)alloc2(MS * 4);
    int* count2  = (int*)alloc2(MS * 4);
    int* offset2 = (int*)alloc2(MS * 4);
    int* assign2 = (int*)alloc2((size_t)NQ * 4);
    float* sval2 = (float*)alloc2((size_t)NQ * 4);
    float* wgt2  = (float*)alloc2((size_t)NQ * 4);
    int* pos2    = (int*)alloc2((size_t)NQ * 4);
    int* list2   = (int*)alloc2((size_t)NQ * 4);

    hipMemsetAsync(colmax2, 0, MS * 4, stream);
    hipMemsetAsync(count2, 0, MS * 4, stream);

    score_kernel<<<NQ / BQ, 256, 0, stream>>>(query, keys, assign2, sval2, colmax2);
    weight_kernel<<<NQ / 256, 256, 0, stream>>>(sval2, assign2, colmax2, wgt2, pos2, count2);
    scan_kernel<<<1, MS, 0, stream>>>(count2, offset2);
    fill_kernel<<<NQ / 256, 256, 0, stream>>>(assign2, pos2, offset2, list2);
    update_kernel<<<MS, DD, 0, stream>>>(value, keys, wgt2, list2, offset2, count2, out);
  }
}

// Round 5
// 261.044 us; speedup vs baseline: 2.3729x; 1.1139x over previous
//
#include <hip/hip_runtime.h>
#include <hip/hip_bf16.h>
#include <cstdint>
#include <cstddef>

#define NQ 131072   // queries
#define MS 512      // memory slots
#define DD 256      // feature dim

typedef _Float16 f16;
typedef _Float16 f16x8 __attribute__((ext_vector_type(8)));
typedef float f32x4 __attribute__((ext_vector_type(4)));

// ---- monotone float <-> uint encoding for atomicMax on f32 ----
__device__ __forceinline__ unsigned enc_f32(float x) {
  unsigned u = __float_as_uint(x);
  return (u & 0x80000000u) ? ~u : (u | 0x80000000u);
}
__device__ __forceinline__ float dec_f32(unsigned u) {
  unsigned b = (u & 0x80000000u) ? (u & 0x7FFFFFFFu) : ~u;
  return __uint_as_float(b);
}

// exact 2-term f16 split of a float4
__device__ __forceinline__ void cvt4(const float4 v, uint2& uhi, uint2& ulo) {
  union U { f16 h[4]; uint2 u; } a, b;
  float x;
  x = v.x; a.h[0] = (f16)x; b.h[0] = (f16)(x - (float)a.h[0]);
  x = v.y; a.h[1] = (f16)x; b.h[1] = (f16)(x - (float)a.h[1]);
  x = v.z; a.h[2] = (f16)x; b.h[2] = (f16)(x - (float)a.h[2]);
  x = v.w; a.h[3] = (f16)x; b.h[3] = (f16)(x - (float)a.h[3]);
  uhi = a.u; ulo = b.u;
}

// ======================= MFMA path =======================
// LDS byte map (region-blocked, 32B pad per region => region stride == 8 banks mod 32):
//   KH [4][256*16+32] @ 0      (4*4128 = 16512)
//   KL                @ 16512
//   QH [4][128*16+32] @ 33024  (4*2080 = 8320)
//   QL                @ 41344
//   total 49664 B
// Reduction overlay (after compute): redRow u64[128][34] @0 (34816), redCol @34816 (2KB)
#define KH_OFF 0
#define KL_OFF 16512
#define QH_OFF 33024
#define QL_OFF 41344
#define KSTR 4128
#define QSTR 2080

// Score GEMM: block = 128 queries x 256 slots, 512 threads (8 waves 2x4),
// wave tile 64x64 (4x4 subtiles of 16x16), mfma_f32_16x16x32_f16, 3-term hi/lo split
// computed in-register from f32 inputs. Fused row-argmax (packed u64 atomicMax)
// + col-max (encoded u32 atomicMax).
// __launch_bounds__(512, 4): 16 waves/CU => 2 blocks/CU resident => stage/compute
// phases of the two blocks overlap; caps regs at 128/wave (64 acc + ~46 VGPR).
__global__ __launch_bounds__(512, 4) void score_mfma_kernel(
    const float* __restrict__ query, const float* __restrict__ keys,
    unsigned long long* __restrict__ rowPacked,
    unsigned* __restrict__ colmax_enc)
{
  __shared__ __align__(16) unsigned char LDS[49664];

  const int sc = blockIdx.x;      // slot half (0,1)
  const int qb = blockIdx.y;      // query block (0..1023)
  const int tid = threadIdx.x;
  const int l = tid & 63, wid = tid >> 6;
  const int wq = wid >> 2, ws = wid & 3;
  const int lg = l >> 4, ll = l & 15;
  const int q0 = qb * 128;

  f32x4 acc[4][4];
#pragma unroll
  for (int i = 0; i < 4; ++i)
#pragma unroll
    for (int j = 0; j < 4; ++j) acc[i][j] = (f32x4){0.f, 0.f, 0.f, 0.f};

  // per-thread staging geometry (constant across kq)
  const int sr = tid >> 3;              // 0..63 base row
  const int c4 = tid & 7;               // float4 column index
  const int rg = c4 >> 1, hf = c4 & 1;
  const int stoff = rg * KSTR + hf * 8; // K-region byte offset (row term added per u)
  const int qtoff = rg * QSTR + hf * 8;

  for (int kq = 0; kq < 8; ++kq) {
    const int kofs = kq * 32;
    __syncthreads();   // prior compute done reading LDS
    // ---- stage: load f32, split to f16 hi/lo in-register, write LDS ----
    {
      float4 t0 = *(const float4*)&keys[(size_t)(sc * 256 + sr)       * DD + kofs + c4 * 4];
      float4 t1 = *(const float4*)&keys[(size_t)(sc * 256 + sr + 64)  * DD + kofs + c4 * 4];
      float4 t2 = *(const float4*)&keys[(size_t)(sc * 256 + sr + 128) * DD + kofs + c4 * 4];
      float4 t3 = *(const float4*)&keys[(size_t)(sc * 256 + sr + 192) * DD + kofs + c4 * 4];
      float4 t4 = *(const float4*)&query[(size_t)(q0 + sr)      * DD + kofs + c4 * 4];
      float4 t5 = *(const float4*)&query[(size_t)(q0 + sr + 64) * DD + kofs + c4 * 4];
      uint2 uh, ul;
      cvt4(t0, uh, ul);
      *(uint2*)&LDS[KH_OFF + stoff + (sr)       * 16] = uh;
      *(uint2*)&LDS[KL_OFF + stoff + (sr)       * 16] = ul;
      cvt4(t1, uh, ul);
      *(uint2*)&LDS[KH_OFF + stoff + (sr + 64)  * 16] = uh;
      *(uint2*)&LDS[KL_OFF + stoff + (sr + 64)  * 16] = ul;
      cvt4(t2, uh, ul);
      *(uint2*)&LDS[KH_OFF + stoff + (sr + 128) * 16] = uh;
      *(uint2*)&LDS[KL_OFF + stoff + (sr + 128) * 16] = ul;
      cvt4(t3, uh, ul);
      *(uint2*)&LDS[KH_OFF + stoff + (sr + 192) * 16] = uh;
      *(uint2*)&LDS[KL_OFF + stoff + (sr + 192) * 16] = ul;
      cvt4(t4, uh, ul);
      *(uint2*)&LDS[QH_OFF + qtoff + (sr)       * 16] = uh;
      *(uint2*)&LDS[QL_OFF + qtoff + (sr)       * 16] = ul;
      cvt4(t5, uh, ul);
      *(uint2*)&LDS[QH_OFF + qtoff + (sr + 64)  * 16] = uh;
      *(uint2*)&LDS[QL_OFF + qtoff + (sr + 64)  * 16] = ul;
    }
    __syncthreads();

    // ---- compute: A-frags resident, B loaded per-j (reg-lean) ----
    f16x8 ah[4], al[4];
#pragma unroll
    for (int i = 0; i < 4; ++i) {
      const int r = wq * 64 + i * 16 + ll;
      ah[i] = *(const f16x8*)&LDS[QH_OFF + lg * QSTR + r * 16];
      al[i] = *(const f16x8*)&LDS[QL_OFF + lg * QSTR + r * 16];
    }
#pragma unroll
    for (int j = 0; j < 4; ++j) {
      const int s = ws * 64 + j * 16 + ll;
      const f16x8 bh = *(const f16x8*)&LDS[KH_OFF + lg * KSTR + s * 16];
      const f16x8 bl = *(const f16x8*)&LDS[KL_OFF + lg * KSTR + s * 16];
#pragma unroll
      for (int i = 0; i < 4; ++i) {
        f32x4 c = acc[i][j];
        c = __builtin_amdgcn_mfma_f32_16x16x32_f16(ah[i], bl, c, 0, 0, 0);
        c = __builtin_amdgcn_mfma_f32_16x16x32_f16(al[i], bh, c, 0, 0, 0);
        c = __builtin_amdgcn_mfma_f32_16x16x32_f16(ah[i], bh, c, 0, 0, 0);
        acc[i][j] = c;
      }
    }
  }

  // ---- reductions ----
  // C layout (verified R3/R4 end-to-end): elem v of acc[i][j]:
  //   row = wq*64 + i*16 + lg*4 + v, col(within 256) = ws*64 + j*16 + ll
  __syncthreads();   // all waves done reading LDS; overlay reductions
  unsigned long long* redRow = (unsigned long long*)(LDS);   // [128][34] (pad->bank spread)
  float* redCol = (float*)(LDS + 34816);                     // [256][2]

#pragma unroll
  for (int i = 0; i < 4; ++i)
#pragma unroll
    for (int v = 0; v < 4; ++v) {
      float bv = acc[i][0][v];
      int bc = ws * 64 + ll;
#pragma unroll
      for (int j = 1; j < 4; ++j) {
        const float x = acc[i][j][v];
        const int c = ws * 64 + j * 16 + ll;
        if (x > bv) { bv = x; bc = c; }
      }
      const int gidx = sc * 256 + bc;
      unsigned long long p =
          ((unsigned long long)enc_f32(bv) << 32) | (unsigned)(~(unsigned)gidx);
      // 1-step pair reduce, then LDS candidate table (cheaper than 4-step shfl chain)
      const unsigned long long q = __shfl_xor(p, 1);
      if (q > p) p = q;
      if ((ll & 1) == 0) {
        const int row = wq * 64 + i * 16 + lg * 4 + v;
        redRow[row * 34 + ws * 8 + (ll >> 1)] = p;
      }
    }

#pragma unroll
  for (int j = 0; j < 4; ++j) {
    float m = acc[0][j][0];
#pragma unroll
    for (int i = 0; i < 4; ++i)
#pragma unroll
      for (int v = 0; v < 4; ++v) m = fmaxf(m, acc[i][j][v]);
    m = fmaxf(m, __shfl_xor(m, 16));
    m = fmaxf(m, __shfl_xor(m, 32));
    if (l < 16) redCol[(ws * 64 + j * 16 + l) * 2 + wq] = m;
  }

  __syncthreads();
  if (tid < 128) {
    unsigned long long p = redRow[tid * 34];
#pragma unroll
    for (int w = 1; w < 32; ++w) {
      const unsigned long long q = redRow[tid * 34 + w];
      if (q > p) p = q;
    }
    atomicMax(&rowPacked[(size_t)qb * 128 + tid], p);
  }
  if (tid < 256) {
    const float v = fmaxf(redCol[tid * 2], redCol[tid * 2 + 1]);
    atomicMax(&colmax_enc[sc * 256 + tid], enc_f32(v));
  }
}

// ---- weights + per-slot counts (MFMA path: reads rowPacked) ----
__global__ void weight2_kernel(const unsigned long long* __restrict__ rowPacked,
                               const unsigned* __restrict__ colmax_enc,
                               float* __restrict__ w, int* __restrict__ assign,
                               int* __restrict__ pos, int* __restrict__ count)
{
  const int i = blockIdx.x * blockDim.x + threadIdx.x;
  if (i >= NQ) return;
  const unsigned long long p = rowPacked[i];
  const int a = (int)(~(unsigned)(p & 0xFFFFFFFFull));
  const float sv = dec_f32((unsigned)(p >> 32));
  const float cm = dec_f32(colmax_enc[a]);
  w[i] = expf(sv - cm);
  assign[i] = a;
  pos[i] = atomicAdd(&count[a], 1);
}

// ======================= fallback path (round-1, verified) =======================
#define BQ 128
#define BM 128
#define DC 32
#define PAD 132

__global__ __launch_bounds__(256) void score_kernel(
    const float* __restrict__ query, const float* __restrict__ keys,
    int* __restrict__ assign_out, float* __restrict__ sval_out,
    unsigned* __restrict__ colmax_enc)
{
  __shared__ float Qs[DC][PAD];
  __shared__ float Ks[DC][PAD];
  __shared__ float redV[BQ * 16];
  __shared__ int   redI[BQ * 16];

  const int tid = threadIdx.x;
  const int ty = tid >> 4;
  const int tx = tid & 15;
  const int q0 = blockIdx.x * BQ;

  float bestV = -3.4e38f;
  int   bestI = 0;

  for (int mc = 0; mc < MS / BM; ++mc) {
    float acc[8][8];
#pragma unroll
    for (int i = 0; i < 8; ++i)
#pragma unroll
      for (int j = 0; j < 8; ++j) acc[i][j] = 0.f;

    for (int dc = 0; dc < DD; dc += DC) {
      __syncthreads();
#pragma unroll
      for (int it = 0; it < 4; ++it) {
        const int r = (tid >> 3) + it * 32;
        const int d = (tid & 7) * 4;
        const float4 qv = *reinterpret_cast<const float4*>(
            &query[(size_t)(q0 + r) * DD + dc + d]);
        Qs[d + 0][r] = qv.x; Qs[d + 1][r] = qv.y;
        Qs[d + 2][r] = qv.z; Qs[d + 3][r] = qv.w;
        const float4 kv = *reinterpret_cast<const float4*>(
            &keys[(size_t)(mc * BM + r) * DD + dc + d]);
        Ks[d + 0][r] = kv.x; Ks[d + 1][r] = kv.y;
        Ks[d + 2][r] = kv.z; Ks[d + 3][r] = kv.w;
      }
      __syncthreads();
#pragma unroll
      for (int d = 0; d < DC; ++d) {
        float a[8], b[8];
        *reinterpret_cast<float4*>(&a[0]) = *reinterpret_cast<const float4*>(&Qs[d][ty * 8]);
        *reinterpret_cast<float4*>(&a[4]) = *reinterpret_cast<const float4*>(&Qs[d][ty * 8 + 4]);
        *reinterpret_cast<float4*>(&b[0]) = *reinterpret_cast<const float4*>(&Ks[d][tx * 8]);
        *reinterpret_cast<float4*>(&b[4]) = *reinterpret_cast<const float4*>(&Ks[d][tx * 8 + 4]);
#pragma unroll
        for (int i = 0; i < 8; ++i)
#pragma unroll
          for (int j = 0; j < 8; ++j)
            acc[i][j] = fmaf(a[i], b[j], acc[i][j]);
      }
    }

    __syncthreads();
#pragma unroll
    for (int i = 0; i < 8; ++i) {
      float v = acc[i][0]; int jj = 0;
#pragma unroll
      for (int j = 1; j < 8; ++j)
        if (acc[i][j] > v) { v = acc[i][j]; jj = j; }
      redV[(ty * 8 + i) * 16 + tx] = v;
      redI[(ty * 8 + i) * 16 + tx] = mc * BM + tx * 8 + jj;
    }
    __syncthreads();
    if (tid < BQ) {
#pragma unroll
      for (int t = 0; t < 16; ++t) {
        float v = redV[tid * 16 + t];
        if (v > bestV) { bestV = v; bestI = redI[tid * 16 + t]; }
      }
    }
    __syncthreads();
#pragma unroll
    for (int j = 0; j < 8; ++j) {
      float v = acc[0][j];
#pragma unroll
      for (int i = 1; i < 8; ++i) v = fmaxf(v, acc[i][j]);
      redV[(tx * 8 + j) * 16 + ty] = v;
    }
    __syncthreads();
    if (tid < BM) {
      float v = redV[tid * 16];
#pragma unroll
      for (int t = 1; t < 16; ++t) v = fmaxf(v, redV[tid * 16 + t]);
      atomicMax(&colmax_enc[mc * BM + tid], enc_f32(v));
    }
  }

  if (tid < BQ) {
    assign_out[q0 + tid] = bestI;
    sval_out[q0 + tid]   = bestV;
  }
}

__global__ void weight_kernel(const float* __restrict__ sval,
                              const int* __restrict__ assign,
                              const unsigned* __restrict__ colmax_enc,
                              float* __restrict__ w,
                              int* __restrict__ pos,
                              int* __restrict__ count)
{
  int i = blockIdx.x * blockDim.x + threadIdx.x;
  if (i >= NQ) return;
  int a = assign[i];
  float cm = dec_f32(colmax_enc[a]);
  w[i] = expf(sval[i] - cm);
  pos[i] = atomicAdd(&count[a], 1);
}

// ======================= shared tail kernels =======================

__global__ void scan_kernel(const int* __restrict__ count, int* __restrict__ offset)
{
  __shared__ int s[MS];
  int t = threadIdx.x;
  int c = count[t];
  s[t] = c;
  __syncthreads();
  for (int off = 1; off < MS; off <<= 1) {
    int v = (t >= off) ? s[t - off] : 0;
    __syncthreads();
    s[t] += v;
    __syncthreads();
  }
  offset[t] = s[t] - c;
}

__global__ void fill_kernel(const int* __restrict__ assign,
                            const int* __restrict__ pos,
                            const int* __restrict__ offset,
                            int* __restrict__ list)
{
  int i = blockIdx.x * blockDim.x + threadIdx.x;
  if (i >= NQ) return;
  int a = assign[i];
  list[offset[a] + pos[i]] = i;
}

__global__ __launch_bounds__(256) void update_kernel(
    const float* __restrict__ value, const float* __restrict__ keys,
    const float* __restrict__ w, const int* __restrict__ list,
    const int* __restrict__ offset, const int* __restrict__ count,
    float* __restrict__ out)
{
  const int m = blockIdx.x;
  const int d = threadIdx.x;
  const int off = offset[m];
  const int cnt = count[m];
  float acc = 0.f;
  int j = 0;
  for (; j + 4 <= cnt; j += 4) {
    const int i0 = list[off + j + 0];
    const int i1 = list[off + j + 1];
    const int i2 = list[off + j + 2];
    const int i3 = list[off + j + 3];
    const float w0 = w[i0], w1 = w[i1], w2 = w[i2], w3 = w[i3];
    const float v0 = value[(size_t)i0 * DD + d];
    const float v1 = value[(size_t)i1 * DD + d];
    const float v2 = value[(size_t)i2 * DD + d];
    const float v3 = value[(size_t)i3 * DD + d];
    acc = fmaf(w0, v0, acc);
    acc = fmaf(w1, v1, acc);
    acc = fmaf(w2, v2, acc);
    acc = fmaf(w3, v3, acc);
  }
  for (; j < cnt; ++j) {
    const int i = list[off + j];
    acc = fmaf(w[i], value[(size_t)i * DD + d], acc);
  }
  float x = acc + keys[(size_t)m * DD + d];
  float ss = x * x;
#pragma unroll
  for (int o = 1; o < 64; o <<= 1) ss += __shfl_xor(ss, o);
  __shared__ float wsum[4];
  if ((threadIdx.x & 63) == 0) wsum[threadIdx.x >> 6] = ss;
  __syncthreads();
  float tot = wsum[0] + wsum[1] + wsum[2] + wsum[3];
  float den = fmaxf(sqrtf(tot), 1e-12f);
  out[(size_t)m * DD + d] = x / den;
}

// ======================= launcher =======================

extern "C" void kernel_launch(void* const* d_in, const int* in_sizes, int n_in,
                              void* d_out, int out_size, void* d_ws, size_t ws_size,
                              hipStream_t stream)
{
  const float* keys  = (const float*)d_in[0];
  const float* query = (const float*)d_in[1];
  const float* value = (const float*)d_in[2];
  float* out = (float*)d_out;

  char* ws = (char*)d_ws;
  size_t o = 0;
  auto alloc = [&](size_t bytes) -> void* {
    void* p = ws + o;
    o += (bytes + 255) & ~(size_t)255;
    return p;
  };

  unsigned long long* rowPacked = (unsigned long long*)alloc((size_t)NQ * 8);
  unsigned* colmax_enc = (unsigned*)alloc(MS * 4);
  int* count  = (int*)alloc(MS * 4);
  int* offset = (int*)alloc(MS * 4);
  int* assign = (int*)alloc((size_t)NQ * 4);
  float* wgt  = (float*)alloc((size_t)NQ * 4);
  int* pos    = (int*)alloc((size_t)NQ * 4);
  int* list   = (int*)alloc((size_t)NQ * 4);
  const size_t mfma_need = o;

  if (ws_size >= mfma_need) {
    hipMemsetAsync(rowPacked, 0, (size_t)NQ * 8, stream);
    hipMemsetAsync(colmax_enc, 0, MS * 4, stream);
    hipMemsetAsync(count, 0, MS * 4, stream);

    score_mfma_kernel<<<dim3(2, 1024), 512, 0, stream>>>(query, keys,
                                                         rowPacked, colmax_enc);
    weight2_kernel<<<NQ / 256, 256, 0, stream>>>(rowPacked, colmax_enc,
                                                 wgt, assign, pos, count);
    scan_kernel<<<1, MS, 0, stream>>>(count, offset);
    fill_kernel<<<NQ / 256, 256, 0, stream>>>(assign, pos, offset, list);
    update_kernel<<<MS, DD, 0, stream>>>(value, keys, wgt, list, offset, count, out);
  } else {
    // --- fallback: round-1 verified fp32-VALU path ---
    size_t o2 = 0;
    auto alloc2 = [&](size_t bytes) -> void* {
      void* p = ws + o2;
      o2 += (bytes + 255) & ~(size_t)255;
      return p;
    };
    unsigned* colmax2 = (unsigned*)alloc2(MS * 4);
    int* count2  = (int*)alloc2(MS * 4);
    int* offset2 = (int*)alloc2(MS * 4);
    int* assign2 = (int*)alloc2((size_t)NQ * 4);
    float* sval2 = (float*)alloc2((size_t)NQ * 4);
    float* wgt2  = (float*)alloc2((size_t)NQ * 4);
    int* pos2    = (int*)alloc2((size_t)NQ * 4);
    int* list2   = (int*)alloc2((size_t)NQ * 4);

    hipMemsetAsync(colmax2, 0, MS * 4, stream);
    hipMemsetAsync(count2, 0, MS * 4, stream);

    score_kernel<<<NQ / BQ, 256, 0, stream>>>(query, keys, assign2, sval2, colmax2);
    weight_kernel<<<NQ / 256, 256, 0, stream>>>(sval2, assign2, colmax2, wgt2, pos2, count2);
    scan_kernel<<<1, MS, 0, stream>>>(count2, offset2);
    fill_kernel<<<NQ / 256, 256, 0, stream>>>(assign2, pos2, offset2, list2);
    update_kernel<<<MS, DD, 0, stream>>>(value, keys, wgt2, list2, offset2, count2, out);
  }
}

// Round 6
// 221.392 us; speedup vs baseline: 2.7979x; 1.1791x over previous
//
#include <hip/hip_runtime.h>
#include <hip/hip_bf16.h>
#include <cstdint>
#include <cstddef>

#define NQ 131072   // queries
#define MS 512      // memory slots
#define DD 256      // feature dim
#define USPLIT 8    // update-kernel per-slot parallel split

typedef _Float16 f16;
typedef _Float16 f16x8 __attribute__((ext_vector_type(8)));
typedef float f32x4 __attribute__((ext_vector_type(4)));

// ---- monotone float <-> uint encoding for atomicMax on f32 ----
__device__ __forceinline__ unsigned enc_f32(float x) {
  unsigned u = __float_as_uint(x);
  return (u & 0x80000000u) ? ~u : (u | 0x80000000u);
}
__device__ __forceinline__ float dec_f32(unsigned u) {
  unsigned b = (u & 0x80000000u) ? (u & 0x7FFFFFFFu) : ~u;
  return __uint_as_float(b);
}

// exact 2-term f16 split of a float4
__device__ __forceinline__ void cvt4(const float4 v, uint2& uhi, uint2& ulo) {
  union U { f16 h[4]; uint2 u; } a, b;
  float x;
  x = v.x; a.h[0] = (f16)x; b.h[0] = (f16)(x - (float)a.h[0]);
  x = v.y; a.h[1] = (f16)x; b.h[1] = (f16)(x - (float)a.h[1]);
  x = v.z; a.h[2] = (f16)x; b.h[2] = (f16)(x - (float)a.h[2]);
  x = v.w; a.h[3] = (f16)x; b.h[3] = (f16)(x - (float)a.h[3]);
  uhi = a.u; ulo = b.u;
}

// ======================= MFMA path =======================
// LDS byte map (region-blocked, 32B pad per region => region stride == 8 banks mod 32):
//   KH [4][256*16+32] @ 0      (4*4128 = 16512)
//   KL                @ 16512
//   QH [4][128*16+32] @ 33024  (4*2080 = 8320)
//   QL                @ 41344
//   total 49664 B
// Reduction overlay (after compute): redRow u64[128][34] @0 (34816), redCol @34816 (2KB)
#define KH_OFF 0
#define KL_OFF 16512
#define QH_OFF 33024
#define QL_OFF 41344
#define KSTR 4128
#define QSTR 2080

// Pre-split keys f32 -> f16 hi/lo in B-fragment-ordered layout:
//   byte offset = ((sc*8+kq)*4 + rg)*4096 + slot*16 + hf*8
// so score staging is a straight 16B copy into its LDS region layout.
__global__ __launch_bounds__(256) void ksplit_kernel(
    const float* __restrict__ keys, f16* __restrict__ kfh, f16* __restrict__ kfl)
{
  const int t = blockIdx.x * 256 + threadIdx.x;    // 0..32767
  const int S = t >> 6, c4 = t & 63;               // slot, float4-col
  const float4 v = *(const float4*)&keys[(size_t)S * DD + c4 * 4];
  const int sc = S >> 8, slot = S & 255;
  const int kq = c4 >> 3, rg = (c4 >> 1) & 3, hf = c4 & 1;
  uint2 uh, ul;
  cvt4(v, uh, ul);
  const size_t off = ((size_t)((sc * 8 + kq) * 4 + rg)) * 4096 + slot * 16 + hf * 8; // bytes
  *(uint2*)((char*)kfh + off) = uh;
  *(uint2*)((char*)kfl + off) = ul;
}

// Score GEMM: block = 128 queries x 256 slots, 512 threads (8 waves 2x4),
// wave tile 64x64 (4x4 subtiles of 16x16), mfma_f32_16x16x32_f16, 3-term hi/lo.
// K comes pre-split in fragment order (pure copy to LDS, no VALU); Q split in-reg.
// Fused row-argmax (packed u64 atomicMax) + col-max (encoded u32 atomicMax).
__global__ __launch_bounds__(512, 4) void score_mfma_kernel(
    const float* __restrict__ query,
    const f16* __restrict__ kfh, const f16* __restrict__ kfl,
    unsigned long long* __restrict__ rowPacked,
    unsigned* __restrict__ colmax_enc)
{
  __shared__ __align__(16) unsigned char LDS[49664];

  const int sc = blockIdx.x;      // slot half (0,1)
  const int qb = blockIdx.y;      // query block (0..1023)
  const int tid = threadIdx.x;
  const int l = tid & 63, wid = tid >> 6;
  const int wq = wid >> 2, ws = wid & 3;
  const int lg = l >> 4, ll = l & 15;
  const int q0 = qb * 128;

  f32x4 acc[4][4];
#pragma unroll
  for (int i = 0; i < 4; ++i)
#pragma unroll
    for (int j = 0; j < 4; ++j) acc[i][j] = (f32x4){0.f, 0.f, 0.f, 0.f};

  // per-thread staging geometry
  const int sr = tid >> 3;              // Q base row (0..63)
  const int c4 = tid & 7;               // Q float4 col
  const int rg = c4 >> 1, hf = c4 & 1;
  const int qtoff = rg * QSTR + hf * 8;
  const int o0 = tid * 16;              // K copy offsets (bytes within 16KB chunk)
  const int o1 = 8192 + tid * 16;
  const int kd0 = (o0 >> 12) * KSTR + (o0 & 4095);
  const int kd1 = (o1 >> 12) * KSTR + (o1 & 4095);

  const char* kfh_b = (const char*)kfh + (size_t)(sc * 8) * 16384;
  const char* kfl_b = (const char*)kfl + (size_t)(sc * 8) * 16384;

  for (int kq = 0; kq < 8; ++kq) {
    // ---- issue loads early (overlap with previous compute phase) ----
    const char* skh = kfh_b + (size_t)kq * 16384;
    const char* skl = kfl_b + (size_t)kq * 16384;
    const uint4 k0 = *(const uint4*)(skh + o0);
    const uint4 k1 = *(const uint4*)(skh + o1);
    const uint4 k2 = *(const uint4*)(skl + o0);
    const uint4 k3 = *(const uint4*)(skl + o1);
    const int kofs = kq * 32;
    const float4 t4 = *(const float4*)&query[(size_t)(q0 + sr)      * DD + kofs + c4 * 4];
    const float4 t5 = *(const float4*)&query[(size_t)(q0 + sr + 64) * DD + kofs + c4 * 4];

    __syncthreads();   // prior compute done reading LDS
    // K: straight copy (fragment-ordered global -> region LDS layout)
    *(uint4*)&LDS[KH_OFF + kd0] = k0;
    *(uint4*)&LDS[KH_OFF + kd1] = k1;
    *(uint4*)&LDS[KL_OFF + kd0] = k2;
    *(uint4*)&LDS[KL_OFF + kd1] = k3;
    // Q: split in-register, write hi/lo
    {
      uint2 uh, ul;
      cvt4(t4, uh, ul);
      *(uint2*)&LDS[QH_OFF + qtoff + (sr)      * 16] = uh;
      *(uint2*)&LDS[QL_OFF + qtoff + (sr)      * 16] = ul;
      cvt4(t5, uh, ul);
      *(uint2*)&LDS[QH_OFF + qtoff + (sr + 64) * 16] = uh;
      *(uint2*)&LDS[QL_OFF + qtoff + (sr + 64) * 16] = ul;
    }
    __syncthreads();

    // ---- compute: A-frags resident, B loaded per-j (reg-lean) ----
    f16x8 ah[4], al[4];
#pragma unroll
    for (int i = 0; i < 4; ++i) {
      const int r = wq * 64 + i * 16 + ll;
      ah[i] = *(const f16x8*)&LDS[QH_OFF + lg * QSTR + r * 16];
      al[i] = *(const f16x8*)&LDS[QL_OFF + lg * QSTR + r * 16];
    }
#pragma unroll
    for (int j = 0; j < 4; ++j) {
      const int s = ws * 64 + j * 16 + ll;
      const f16x8 bh = *(const f16x8*)&LDS[KH_OFF + lg * KSTR + s * 16];
      const f16x8 bl = *(const f16x8*)&LDS[KL_OFF + lg * KSTR + s * 16];
#pragma unroll
      for (int i = 0; i < 4; ++i) {
        f32x4 c = acc[i][j];
        c = __builtin_amdgcn_mfma_f32_16x16x32_f16(ah[i], bl, c, 0, 0, 0);
        c = __builtin_amdgcn_mfma_f32_16x16x32_f16(al[i], bh, c, 0, 0, 0);
        c = __builtin_amdgcn_mfma_f32_16x16x32_f16(ah[i], bh, c, 0, 0, 0);
        acc[i][j] = c;
      }
    }
  }

  // ---- reductions ----
  // C layout (verified R3-R5 end-to-end): elem v of acc[i][j]:
  //   row = wq*64 + i*16 + lg*4 + v, col(within 256) = ws*64 + j*16 + ll
  __syncthreads();   // all waves done reading LDS; overlay reductions
  unsigned long long* redRow = (unsigned long long*)(LDS);   // [128][34]
  float* redCol = (float*)(LDS + 34816);                     // [256][2]

#pragma unroll
  for (int i = 0; i < 4; ++i)
#pragma unroll
    for (int v = 0; v < 4; ++v) {
      float bv = acc[i][0][v];
      int bc = ws * 64 + ll;
#pragma unroll
      for (int j = 1; j < 4; ++j) {
        const float x = acc[i][j][v];
        const int c = ws * 64 + j * 16 + ll;
        if (x > bv) { bv = x; bc = c; }
      }
      const int gidx = sc * 256 + bc;
      unsigned long long p =
          ((unsigned long long)enc_f32(bv) << 32) | (unsigned)(~(unsigned)gidx);
      const unsigned long long q = __shfl_xor(p, 1);
      if (q > p) p = q;
      if ((ll & 1) == 0) {
        const int row = wq * 64 + i * 16 + lg * 4 + v;
        redRow[row * 34 + ws * 8 + (ll >> 1)] = p;
      }
    }

#pragma unroll
  for (int j = 0; j < 4; ++j) {
    float m = acc[0][j][0];
#pragma unroll
    for (int i = 0; i < 4; ++i)
#pragma unroll
      for (int v = 0; v < 4; ++v) m = fmaxf(m, acc[i][j][v]);
    m = fmaxf(m, __shfl_xor(m, 16));
    m = fmaxf(m, __shfl_xor(m, 32));
    if (l < 16) redCol[(ws * 64 + j * 16 + l) * 2 + wq] = m;
  }

  __syncthreads();
  if (tid < 128) {
    unsigned long long p = redRow[tid * 34];
#pragma unroll
    for (int w = 1; w < 32; ++w) {
      const unsigned long long q = redRow[tid * 34 + w];
      if (q > p) p = q;
    }
    atomicMax(&rowPacked[(size_t)qb * 128 + tid], p);
  }
  if (tid < 256) {
    const float v = fmaxf(redCol[tid * 2], redCol[tid * 2 + 1]);
    atomicMax(&colmax_enc[sc * 256 + tid], enc_f32(v));
  }
}

// ---- weights + per-slot counts (MFMA path: reads rowPacked) ----
__global__ void weight2_kernel(const unsigned long long* __restrict__ rowPacked,
                               const unsigned* __restrict__ colmax_enc,
                               float* __restrict__ w, int* __restrict__ assign,
                               int* __restrict__ pos, int* __restrict__ count)
{
  const int i = blockIdx.x * blockDim.x + threadIdx.x;
  if (i >= NQ) return;
  const unsigned long long p = rowPacked[i];
  const int a = (int)(~(unsigned)(p & 0xFFFFFFFFull));
  const float sv = dec_f32((unsigned)(p >> 32));
  const float cm = dec_f32(colmax_enc[a]);
  w[i] = expf(sv - cm);
  assign[i] = a;
  pos[i] = atomicAdd(&count[a], 1);
}

// ======================= fallback path (round-1, verified) =======================
#define BQ 128
#define BM 128
#define DC 32
#define PAD 132

__global__ __launch_bounds__(256) void score_kernel(
    const float* __restrict__ query, const float* __restrict__ keys,
    int* __restrict__ assign_out, float* __restrict__ sval_out,
    unsigned* __restrict__ colmax_enc)
{
  __shared__ float Qs[DC][PAD];
  __shared__ float Ks[DC][PAD];
  __shared__ float redV[BQ * 16];
  __shared__ int   redI[BQ * 16];

  const int tid = threadIdx.x;
  const int ty = tid >> 4;
  const int tx = tid & 15;
  const int q0 = blockIdx.x * BQ;

  float bestV = -3.4e38f;
  int   bestI = 0;

  for (int mc = 0; mc < MS / BM; ++mc) {
    float acc[8][8];
#pragma unroll
    for (int i = 0; i < 8; ++i)
#pragma unroll
      for (int j = 0; j < 8; ++j) acc[i][j] = 0.f;

    for (int dc = 0; dc < DD; dc += DC) {
      __syncthreads();
#pragma unroll
      for (int it = 0; it < 4; ++it) {
        const int r = (tid >> 3) + it * 32;
        const int d = (tid & 7) * 4;
        const float4 qv = *reinterpret_cast<const float4*>(
            &query[(size_t)(q0 + r) * DD + dc + d]);
        Qs[d + 0][r] = qv.x; Qs[d + 1][r] = qv.y;
        Qs[d + 2][r] = qv.z; Qs[d + 3][r] = qv.w;
        const float4 kv = *reinterpret_cast<const float4*>(
            &keys[(size_t)(mc * BM + r) * DD + dc + d]);
        Ks[d + 0][r] = kv.x; Ks[d + 1][r] = kv.y;
        Ks[d + 2][r] = kv.z; Ks[d + 3][r] = kv.w;
      }
      __syncthreads();
#pragma unroll
      for (int d = 0; d < DC; ++d) {
        float a[8], b[8];
        *reinterpret_cast<float4*>(&a[0]) = *reinterpret_cast<const float4*>(&Qs[d][ty * 8]);
        *reinterpret_cast<float4*>(&a[4]) = *reinterpret_cast<const float4*>(&Qs[d][ty * 8 + 4]);
        *reinterpret_cast<float4*>(&b[0]) = *reinterpret_cast<const float4*>(&Ks[d][tx * 8]);
        *reinterpret_cast<float4*>(&b[4]) = *reinterpret_cast<const float4*>(&Ks[d][tx * 8 + 4]);
#pragma unroll
        for (int i = 0; i < 8; ++i)
#pragma unroll
          for (int j = 0; j < 8; ++j)
            acc[i][j] = fmaf(a[i], b[j], acc[i][j]);
      }
    }

    __syncthreads();
#pragma unroll
    for (int i = 0; i < 8; ++i) {
      float v = acc[i][0]; int jj = 0;
#pragma unroll
      for (int j = 1; j < 8; ++j)
        if (acc[i][j] > v) { v = acc[i][j]; jj = j; }
      redV[(ty * 8 + i) * 16 + tx] = v;
      redI[(ty * 8 + i) * 16 + tx] = mc * BM + tx * 8 + jj;
    }
    __syncthreads();
    if (tid < BQ) {
#pragma unroll
      for (int t = 0; t < 16; ++t) {
        float v = redV[tid * 16 + t];
        if (v > bestV) { bestV = v; bestI = redI[tid * 16 + t]; }
      }
    }
    __syncthreads();
#pragma unroll
    for (int j = 0; j < 8; ++j) {
      float v = acc[0][j];
#pragma unroll
      for (int i = 1; i < 8; ++i) v = fmaxf(v, acc[i][j]);
      redV[(tx * 8 + j) * 16 + ty] = v;
    }
    __syncthreads();
    if (tid < BM) {
      float v = redV[tid * 16];
#pragma unroll
      for (int t = 1; t < 16; ++t) v = fmaxf(v, redV[tid * 16 + t]);
      atomicMax(&colmax_enc[mc * BM + tid], enc_f32(v));
    }
  }

  if (tid < BQ) {
    assign_out[q0 + tid] = bestI;
    sval_out[q0 + tid]   = bestV;
  }
}

__global__ void weight_kernel(const float* __restrict__ sval,
                              const int* __restrict__ assign,
                              const unsigned* __restrict__ colmax_enc,
                              float* __restrict__ w,
                              int* __restrict__ pos,
                              int* __restrict__ count)
{
  int i = blockIdx.x * blockDim.x + threadIdx.x;
  if (i >= NQ) return;
  int a = assign[i];
  float cm = dec_f32(colmax_enc[a]);
  w[i] = expf(sval[i] - cm);
  pos[i] = atomicAdd(&count[a], 1);
}

// ======================= shared tail kernels =======================

__global__ void scan_kernel(const int* __restrict__ count, int* __restrict__ offset)
{
  __shared__ int s[MS];
  int t = threadIdx.x;
  int c = count[t];
  s[t] = c;
  __syncthreads();
  for (int off = 1; off < MS; off <<= 1) {
    int v = (t >= off) ? s[t - off] : 0;
    __syncthreads();
    s[t] += v;
    __syncthreads();
  }
  offset[t] = s[t] - c;
}

__global__ void fill_kernel(const int* __restrict__ assign,
                            const int* __restrict__ pos,
                            const int* __restrict__ offset,
                            int* __restrict__ list)
{
  int i = blockIdx.x * blockDim.x + threadIdx.x;
  if (i >= NQ) return;
  int a = assign[i];
  list[offset[a] + pos[i]] = i;
}

// stage 1: per-(slot, chunk) partial weighted sum (8x more parallelism than per-slot)
__global__ __launch_bounds__(256) void update1_kernel(
    const float* __restrict__ value, const float* __restrict__ w,
    const int* __restrict__ list, const int* __restrict__ offset,
    const int* __restrict__ count, float* __restrict__ partial)
{
  const int m = blockIdx.x, c = blockIdx.y, d = threadIdx.x;
  const int off = offset[m];
  const int cnt = count[m];
  float acc = 0.f;
  int j = c;
  for (; j + USPLIT < cnt; j += 2 * USPLIT) {
    const int i0 = list[off + j];
    const int i1 = list[off + j + USPLIT];
    const float w0 = w[i0], w1 = w[i1];
    const float v0 = value[(size_t)i0 * DD + d];
    const float v1 = value[(size_t)i1 * DD + d];
    acc = fmaf(w0, v0, acc);
    acc = fmaf(w1, v1, acc);
  }
  if (j < cnt) {
    const int i = list[off + j];
    acc = fmaf(w[i], value[(size_t)i * DD + d], acc);
  }
  partial[((size_t)m * USPLIT + c) * DD + d] = acc;
}

// stage 2: sum partials + keys, L2-normalize, store
__global__ __launch_bounds__(256) void update2_kernel(
    const float* __restrict__ partial, const float* __restrict__ keys,
    float* __restrict__ out)
{
  const int m = blockIdx.x, d = threadIdx.x;
  float x = keys[(size_t)m * DD + d];
#pragma unroll
  for (int c = 0; c < USPLIT; ++c)
    x += partial[((size_t)m * USPLIT + c) * DD + d];
  float ss = x * x;
#pragma unroll
  for (int o = 1; o < 64; o <<= 1) ss += __shfl_xor(ss, o);
  __shared__ float wsum[4];
  if ((threadIdx.x & 63) == 0) wsum[threadIdx.x >> 6] = ss;
  __syncthreads();
  float tot = wsum[0] + wsum[1] + wsum[2] + wsum[3];
  float den = fmaxf(sqrtf(tot), 1e-12f);
  out[(size_t)m * DD + d] = x / den;
}

// ======================= launcher =======================

extern "C" void kernel_launch(void* const* d_in, const int* in_sizes, int n_in,
                              void* d_out, int out_size, void* d_ws, size_t ws_size,
                              hipStream_t stream)
{
  const float* keys  = (const float*)d_in[0];
  const float* query = (const float*)d_in[1];
  const float* value = (const float*)d_in[2];
  float* out = (float*)d_out;

  char* ws = (char*)d_ws;
  size_t o = 0;
  auto alloc = [&](size_t bytes) -> void* {
    void* p = ws + o;
    o += (bytes + 255) & ~(size_t)255;
    return p;
  };

  f16* kfh = (f16*)alloc((size_t)MS * DD * 2);
  f16* kfl = (f16*)alloc((size_t)MS * DD * 2);
  unsigned long long* rowPacked = (unsigned long long*)alloc((size_t)NQ * 8);
  unsigned* colmax_enc = (unsigned*)alloc(MS * 4);
  int* count  = (int*)alloc(MS * 4);
  int* offset = (int*)alloc(MS * 4);
  int* assign = (int*)alloc((size_t)NQ * 4);
  float* wgt  = (float*)alloc((size_t)NQ * 4);
  int* pos    = (int*)alloc((size_t)NQ * 4);
  int* list   = (int*)alloc((size_t)NQ * 4);
  float* partial = (float*)alloc((size_t)MS * USPLIT * DD * 4);
  const size_t mfma_need = o;

  if (ws_size >= mfma_need) {
    hipMemsetAsync(rowPacked, 0, (size_t)NQ * 8, stream);
    hipMemsetAsync(colmax_enc, 0, MS * 4, stream);
    hipMemsetAsync(count, 0, MS * 4, stream);

    ksplit_kernel<<<128, 256, 0, stream>>>(keys, kfh, kfl);
    score_mfma_kernel<<<dim3(2, 1024), 512, 0, stream>>>(query, kfh, kfl,
                                                         rowPacked, colmax_enc);
    weight2_kernel<<<NQ / 256, 256, 0, stream>>>(rowPacked, colmax_enc,
                                                 wgt, assign, pos, count);
    scan_kernel<<<1, MS, 0, stream>>>(count, offset);
    fill_kernel<<<NQ / 256, 256, 0, stream>>>(assign, pos, offset, list);
    update1_kernel<<<dim3(MS, USPLIT), DD, 0, stream>>>(value, wgt, list,
                                                        offset, count, partial);
    update2_kernel<<<MS, DD, 0, stream>>>(partial, keys, out);
  } else {
    // --- fallback: round-1 verified fp32-VALU path ---
    size_t o2 = 0;
    auto alloc2 = [&](size_t bytes) -> void* {
      void* p = ws + o2;
      o2 += (bytes + 255) & ~(size_t)255;
      return p;
    };
    unsigned* colmax2 = (unsigned*)alloc2(MS * 4);
    int* count2  = (int*)alloc2(MS * 4);
    int* offset2 = (int*)alloc2(MS * 4);
    int* assign2 = (int*)alloc2((size_t)NQ * 4);
    float* sval2 = (float*)alloc2((size_t)NQ * 4);
    float* wgt2  = (float*)alloc2((size_t)NQ * 4);
    int* pos2    = (int*)alloc2((size_t)NQ * 4);
    int* list2   = (int*)alloc2((size_t)NQ * 4);
    float* partial2 = (float*)alloc2((size_t)MS * USPLIT * DD * 4);

    hipMemsetAsync(colmax2, 0, MS * 4, stream);
    hipMemsetAsync(count2, 0, MS * 4, stream);

    score_kernel<<<NQ / BQ, 256, 0, stream>>>(query, keys, assign2, sval2, colmax2);
    weight_kernel<<<NQ / 256, 256, 0, stream>>>(sval2, assign2, colmax2, wgt2, pos2, count2);
    scan_kernel<<<1, MS, 0, stream>>>(count2, offset2);
    fill_kernel<<<NQ / 256, 256, 0, stream>>>(assign2, pos2, offset2, list2);
    update1_kernel<<<dim3(MS, USPLIT), DD, 0, stream>>>(value, wgt2, list2,
                                                        offset2, count2, partial2);
    update2_kernel<<<MS, DD, 0, stream>>>(partial2, keys, out);
  }
}